// Round 4
// baseline (167.011 us; speedup 1.0000x reference)
//
#include <hip/hip_runtime.h>

// Problem constants (match reference module)
#define VNX 360
#define VNY 160
#define VNZ 48
#define VC 4
static constexpr int PLANE = VNZ * VNY * VNX;   // 2,764,800 voxels per batch

// ---------------------------------------------------------------------------
// Pass 1: initialize the winner field. The winner for voxel (b, r) lives in
// d_out at the channel-0 plane slot: out[b*4P + 0*P + r], read as uint32.
// Sentinel = 0xFFFFFFFF. No workspace needed.
// ---------------------------------------------------------------------------
__global__ void vox_init_kernel(unsigned int* __restrict__ out_u, int nvox4) {
    int t = blockIdx.x * blockDim.x + threadIdx.x;
    if (t >= nvox4) return;
    int v = t * 4;                       // 4 consecutive voxels, same batch
    int b = v / PLANE;
    int r = v - b * PLANE;
    uint4* p = (uint4*)(out_u + (size_t)b * (VC * (size_t)PLANE) + r);
    *p = make_uint4(~0u, ~0u, ~0u, ~0u);
}

// ---------------------------------------------------------------------------
// Pass 2: per-point voxelization, first-point-wins via atomicMin(pid) on the
// embedded winner field.
//
// Binning arithmetic: the harness's expected output comes from JAX on CPU,
// where XLA fast-math rewrites (p - lo)/0.2f into (p - lo)*5.0f (1/0.2f
// rounds to exactly 5.0f). Reproduce that EXACTLY: multiply, not divide.
// ---------------------------------------------------------------------------
__global__ void vox_points_kernel(const float4* __restrict__ pts,
                                  const int* __restrict__ bidx,
                                  unsigned int* __restrict__ out_u,
                                  int n) {
    int i = blockIdx.x * blockDim.x + threadIdx.x;
    if (i >= n) return;

    float4 p = pts[i];  // x, y, z, power
    int xi = (int)floorf((p.x -  0.0f) * 5.0f);
    int yi = (int)floorf((p.y + 16.0f) * 5.0f);
    int zi = (int)floorf((p.z +  2.0f) * 5.0f);

    // unsigned compare folds the <0 and >=N checks
    if ((unsigned)xi >= VNX || (unsigned)yi >= VNY || (unsigned)zi >= VNZ)
        return;

    int b = bidx[i];                                     // int32 on device
    int r = (zi * VNY + yi) * VNX + xi;
    atomicMin(out_u + (size_t)b * (VC * (size_t)PLANE) + r, (unsigned int)i);
}

// ---------------------------------------------------------------------------
// Pass 3: read winner from the c0 plane, gather features, overwrite all four
// channel planes (zeros where no point landed). Fully rewrites d_out.
// ---------------------------------------------------------------------------
__global__ void vox_gather_kernel(const float4* __restrict__ feats,
                                  float* __restrict__ out,
                                  unsigned int n, int nvox4) {
    int t = blockIdx.x * blockDim.x + threadIdx.x;
    if (t >= nvox4) return;

    int v = t * 4;
    int b = v / PLANE;
    int r = v - b * PLANE;
    float* base = out + (size_t)b * (VC * (size_t)PLANE) + r;

    uint4 w = *(const uint4*)base;       // embedded winner sentinels

    const float4 zero = make_float4(0.f, 0.f, 0.f, 0.f);
    float4 f0 = (w.x < n) ? feats[w.x] : zero;
    float4 f1 = (w.y < n) ? feats[w.y] : zero;
    float4 f2 = (w.z < n) ? feats[w.z] : zero;
    float4 f3 = (w.w < n) ? feats[w.w] : zero;

    *(float4*)(base + 0 * (size_t)PLANE) = make_float4(f0.x, f1.x, f2.x, f3.x);
    *(float4*)(base + 1 * (size_t)PLANE) = make_float4(f0.y, f1.y, f2.y, f3.y);
    *(float4*)(base + 2 * (size_t)PLANE) = make_float4(f0.z, f1.z, f2.z, f3.z);
    *(float4*)(base + 3 * (size_t)PLANE) = make_float4(f0.w, f1.w, f2.w, f3.w);
}

// ---------------------------------------------------------------------------
extern "C" void kernel_launch(void* const* d_in, const int* in_sizes, int n_in,
                              void* d_out, int out_size, void* d_ws, size_t ws_size,
                              hipStream_t stream) {
    const float* rdr  = (const float*)d_in[0];   // [N,4] f32
    const int*   bidx = (const int*)d_in[1];     // [N] int (harness narrows i64)
    int n = in_sizes[1];                         // number of points

    int G     = out_size / VC;                   // total voxels (B*PLANE)
    int nvox4 = G / 4;                           // G % 4 == 0

    int block = 256;

    // Pass 1: winner sentinel init (inside d_out, c0 planes)
    vox_init_kernel<<<(nvox4 + block - 1) / block, block, 0, stream>>>(
        (unsigned int*)d_out, nvox4);

    // Pass 2: scatter min point-id per voxel
    vox_points_kernel<<<(n + block - 1) / block, block, 0, stream>>>(
        (const float4*)rdr, bidx, (unsigned int*)d_out, n);

    // Pass 3: gather + channel transpose, fully rewrites d_out
    vox_gather_kernel<<<(nvox4 + block - 1) / block, block, 0, stream>>>(
        (const float4*)rdr, (float*)d_out, (unsigned int)n, nvox4);
}

// Round 5
// 162.242 us; speedup vs baseline: 1.0294x; 1.0294x over previous
//
#include <hip/hip_runtime.h>

// Problem constants (match reference module)
#define VNX 360
#define VNY 160
#define VNZ 48
#define VC 4
static constexpr int PLANE = VNZ * VNY * VNX;   // 2,764,800 voxels per batch

typedef unsigned int u32x4 __attribute__((ext_vector_type(4)));
typedef float        f32x4 __attribute__((ext_vector_type(4)));

// ---------------------------------------------------------------------------
// Pass 1: winner[G] = 0xFFFFFFFF sentinel (winner lives in d_ws).
// Grid-stride, 16B stores. Normal (cached) stores: this data is consumed by
// passes 2 and 3 and should stay L3-resident (88.5 MB < 256 MB L3).
// ---------------------------------------------------------------------------
__global__ void vox_init_kernel(u32x4* __restrict__ w4, int n4) {
    int stride = gridDim.x * blockDim.x;
    u32x4 s = { ~0u, ~0u, ~0u, ~0u };
    for (int t = blockIdx.x * blockDim.x + threadIdx.x; t < n4; t += stride)
        w4[t] = s;
}

// ---------------------------------------------------------------------------
// Pass 2: per-point voxelization, first-point-wins via atomicMin(pid).
// Binning: (p - lo) * 5.0f (NOT /0.2f) to match XLA-CPU fast-math reciprocal
// rewrite — verified bit-exact in round 4.
// ---------------------------------------------------------------------------
__global__ void vox_points_kernel(const float4* __restrict__ pts,
                                  const int* __restrict__ bidx,
                                  unsigned int* __restrict__ winner,
                                  int n) {
    int i = blockIdx.x * blockDim.x + threadIdx.x;
    if (i >= n) return;

    float4 p = pts[i];  // x, y, z, power
    int xi = (int)floorf((p.x -  0.0f) * 5.0f);
    int yi = (int)floorf((p.y + 16.0f) * 5.0f);
    int zi = (int)floorf((p.z +  2.0f) * 5.0f);

    if ((unsigned)xi >= VNX || (unsigned)yi >= VNY || (unsigned)zi >= VNZ)
        return;

    int b = bidx[i];
    int flat = ((b * VNZ + zi) * VNY + yi) * VNX + xi;
    atomicMin(&winner[flat], (unsigned int)i);
}

// ---------------------------------------------------------------------------
// Pass 3: gather + transpose to [B, C, Z, Y, X].
// Winner read-once -> non-temporal load. Output write-once, never re-read ->
// non-temporal stores (don't evict winner/feats from L3).
// ---------------------------------------------------------------------------
__global__ void vox_gather_kernel(const u32x4* __restrict__ winner4,
                                  const f32x4* __restrict__ feats,
                                  float* __restrict__ out,
                                  unsigned int n, int nvox4) {
    int stride = gridDim.x * blockDim.x;
    const f32x4 zero = { 0.f, 0.f, 0.f, 0.f };

    for (int t = blockIdx.x * blockDim.x + threadIdx.x; t < nvox4; t += stride) {
        u32x4 w = __builtin_nontemporal_load(&winner4[t]);

        f32x4 f0 = (w.x < n) ? feats[w.x] : zero;
        f32x4 f1 = (w.y < n) ? feats[w.y] : zero;
        f32x4 f2 = (w.z < n) ? feats[w.z] : zero;
        f32x4 f3 = (w.w < n) ? feats[w.w] : zero;

        int v = t * 4;                   // 4 consecutive voxels, same batch
        int b = v / PLANE;               // PLANE % 4 == 0
        int r = v - b * PLANE;
        float* base = out + (size_t)b * (VC * (size_t)PLANE) + r;

        f32x4 c0 = { f0.x, f1.x, f2.x, f3.x };
        f32x4 c1 = { f0.y, f1.y, f2.y, f3.y };
        f32x4 c2 = { f0.z, f1.z, f2.z, f3.z };
        f32x4 c3 = { f0.w, f1.w, f2.w, f3.w };
        __builtin_nontemporal_store(c0, (f32x4*)(base + 0 * (size_t)PLANE));
        __builtin_nontemporal_store(c1, (f32x4*)(base + 1 * (size_t)PLANE));
        __builtin_nontemporal_store(c2, (f32x4*)(base + 2 * (size_t)PLANE));
        __builtin_nontemporal_store(c3, (f32x4*)(base + 3 * (size_t)PLANE));
    }
}

// ---------------------------------------------------------------------------
extern "C" void kernel_launch(void* const* d_in, const int* in_sizes, int n_in,
                              void* d_out, int out_size, void* d_ws, size_t ws_size,
                              hipStream_t stream) {
    const float* rdr  = (const float*)d_in[0];   // [N,4] f32
    const int*   bidx = (const int*)d_in[1];     // [N] int32 on device
    int n = in_sizes[1];

    int G     = out_size / VC;                   // 22,118,400 voxels
    int n4    = G / 4;                           // winner uint4 count

    unsigned int* winner = (unsigned int*)d_ws;  // 88.5 MB (ws is ~1.4 GB)

    int block = 256;
    int grid_dense = 2048;                       // 8 blocks/CU, grid-stride

    // Pass 1: sentinel init
    vox_init_kernel<<<grid_dense, block, 0, stream>>>((u32x4*)winner, n4);

    // Pass 2: scatter min point-id per voxel
    vox_points_kernel<<<(n + block - 1) / block, block, 0, stream>>>(
        (const float4*)rdr, bidx, winner, n);

    // Pass 3: gather + channel transpose (fully rewrites d_out)
    vox_gather_kernel<<<grid_dense, block, 0, stream>>>(
        (const u32x4*)winner, (const f32x4*)rdr, (float*)d_out,
        (unsigned int)n, n4);
}